// Round 17
// baseline (115.419 us; speedup 1.0000x reference)
//
#include <hip/hip_runtime.h>
#include <hip/hip_bf16.h>

// Problem constants (reference: N,E,H,L = 64,64,768,512; eps=1e-12)
#define Nn 64
#define Ee 64
#define Hh 768
#define Ll 512
#define NEH (Nn * Ee * Hh) // 3145728 state elems
#define NEL (Nn * Ee * Ll) // 2097152 mapping elems
#define GSZ (65 * 64)      // per-n gram partial block: 64x64 G + row 64 = S1

typedef __attribute__((ext_vector_type(8))) short bf16x8; // 8 bf16 (MFMA A/B frag)
typedef __attribute__((ext_vector_type(4))) short bf16x4; // 4 bf16 (8B)
typedef __attribute__((ext_vector_type(4))) float f32x4;  // MFMA C/D frag

__device__ __forceinline__ unsigned short f2bf(float x) {
    union { __hip_bfloat16 b; unsigned short u; } cv;
    cv.b = __float2bfloat16(x);
    return cv.u;
}
__device__ __forceinline__ float bf2f(unsigned short u) {
    union { float f; unsigned int i; } v;
    v.i = ((unsigned int)u) << 16;
    return v.f;
}

// ---------------------------------------------------------------------------
// MEASUREMENT ROUND R17: exact R16 pipeline; ONLY gemm_store is rep-wrapped
// (x4) so it out-ranks the 57-62us poison fills and surfaces with counters.
// S = dispatch/4 is the load-bearing number for the whole decomposition
// (inferred 17.5us from R11, never measured). R14 taught us only one kernel
// can surface per round (its 5 instances fill the top-5).
// ---------------------------------------------------------------------------
__global__ __launch_bounds__(256) void cvt_transpose(
    const float* __restrict__ state, const float* __restrict__ mapping,
    __hip_bfloat16* __restrict__ sT, __hip_bfloat16* __restrict__ mT,
    __hip_bfloat16* __restrict__ sC)
{
    __shared__ unsigned short lds[64][66]; // [x][e]

    int b = blockIdx.x;
    const float* src;
    __hip_bfloat16* dst;
    int W, x0, n;
    bool is_state;
    if (b < Nn * (Hh / 64)) {            // state tiles
        is_state = true;
        n = b / (Hh / 64);
        x0 = (b % (Hh / 64)) * 64;
        src = state + (size_t)n * Ee * Hh;
        dst = sT + (size_t)n * Hh * Ee;
        W = Hh;
    } else {                              // mapping tiles
        is_state = false;
        b -= Nn * (Hh / 64);
        n = b / (Ll / 64);
        x0 = (b % (Ll / 64)) * 64;
        src = mapping + (size_t)n * Ee * Ll;
        dst = mT + (size_t)n * Ll * Ee;
        W = Ll;
    }
    unsigned short* sCn = reinterpret_cast<unsigned short*>(sC) + (size_t)n * Ee * Hh;

    const int xr = (threadIdx.x & 31) * 2;
    const int er = threadIdx.x >> 5;  // 0..7
#pragma unroll
    for (int i = 0; i < 8; ++i) {
        int e = i * 8 + er;
        float2 v = *reinterpret_cast<const float2*>(src + (size_t)e * W + x0 + xr);
        unsigned short u0 = f2bf(v.x);
        unsigned short u1 = f2bf(v.y);
        lds[xr][e]     = u0;
        lds[xr + 1][e] = u1;
        if (is_state) {
            unsigned int pk = (unsigned int)u0 | ((unsigned int)u1 << 16);
            *reinterpret_cast<unsigned int*>(sCn + (size_t)e * Hh + x0 + xr) = pk;
        }
    }
    __syncthreads();

    const int e4 = (threadIdx.x & 15) * 4;
    const int xw = threadIdx.x >> 4;   // 0..15
    unsigned short* dsts = reinterpret_cast<unsigned short*>(dst);
#pragma unroll
    for (int i = 0; i < 4; ++i) {
        int x = i * 16 + xw;
        uint2 v;
        v.x = *reinterpret_cast<const unsigned int*>(&lds[x][e4]);
        v.y = *reinterpret_cast<const unsigned int*>(&lds[x][e4 + 2]);
        *reinterpret_cast<uint2*>(dsts + (size_t)(x0 + x) * Ee + e4) = v;
    }
}

// --------------------------- gram_pass v3 (unchanged) ----------------------
__global__ __launch_bounds__(256) void gram_pass(
    const __hip_bfloat16* __restrict__ sC,  // [N][E][H] bf16
    float* __restrict__ gram_part)          // [N*4][GSZ]
{
    const int b    = blockIdx.x;      // 0..255
    const int n    = b >> 2;
    const int ch   = b & 3;           // h-chunk: [ch*192, ch*192+192)
    const int tid  = threadIdx.x;
    const int w    = tid >> 6;
    const int lane = tid & 63;
    const int g    = lane >> 4;
    const int c    = lane & 15;
    const __hip_bfloat16* sn = sC + (size_t)n * (Ee * Hh);
    float* Gp = gram_part + (size_t)b * GSZ;

    f32x4 acc[4];
#pragma unroll
    for (int j = 0; j < 4; ++j) acc[j] = (f32x4){0.f, 0.f, 0.f, 0.f};

#pragma unroll
    for (int ks = 0; ks < 6; ++ks) {
        const int h0 = ch * 192 + ks * 32 + g * 8;
        bf16x8 fa = *reinterpret_cast<const bf16x8*>(sn + (size_t)(w * 16 + c) * Hh + h0);
#pragma unroll
        for (int j = 0; j < 4; ++j) {
            bf16x8 fb = *reinterpret_cast<const bf16x8*>(sn + (size_t)(j * 16 + c) * Hh + h0);
            acc[j] = __builtin_amdgcn_mfma_f32_16x16x32_bf16(fa, fb, acc[j], 0, 0, 0);
        }
    }
#pragma unroll
    for (int j = 0; j < 4; ++j)
#pragma unroll
        for (int r = 0; r < 4; ++r)
            Gp[(w * 16 + g * 4 + r) * 64 + j * 16 + c] = acc[j][r];

    // S1 partial over this chunk (48 h per thread, bf16 source)
    __shared__ float S1p[64][4];
    {
        const int e  = tid >> 2;
        const int qt = tid & 3;
        const unsigned short* p = reinterpret_cast<const unsigned short*>(sn)
                                  + (size_t)e * Hh + ch * 192 + qt * 48;
        float s1 = 0.f;
#pragma unroll
        for (int i = 0; i < 6; ++i) {
            bf16x8 v = *reinterpret_cast<const bf16x8*>(p + i * 8);
#pragma unroll
            for (int r = 0; r < 8; ++r) s1 += bf2f((unsigned short)v[r]);
        }
        S1p[e][qt] = s1;
    }
    __syncthreads();
    if (tid < 64)
        Gp[64 * 64 + tid] = (S1p[tid][0] + S1p[tid][1]) + (S1p[tid][2] + S1p[tid][3]);
}

// --------------------------- gram_reduce (unchanged) -----------------------
__global__ __launch_bounds__(256) void gram_reduce(
    const float* __restrict__ gram_part,     // [N*4][GSZ]
    __hip_bfloat16* __restrict__ gbf,        // [N][64*64]
    float* __restrict__ s1f)                 // [N][64]
{
    const int i = blockIdx.x * 256 + threadIdx.x;  // < Nn*GSZ = 266240
    const int n = i / GSZ;
    const int r = i - n * GSZ;
    const float* p = gram_part + (size_t)n * 4 * GSZ + r;
    const float v = (p[0] + p[GSZ]) + (p[2 * GSZ] + p[3 * GSZ]);
    if (r < 4096) gbf[(size_t)n * 4096 + r] = __float2bfloat16(v);
    else          s1f[n * 64 + (r - 4096)] = v;
}

// --------------------------- quad_stats v3 (unchanged) ---------------------
__global__ __launch_bounds__(256) void quad_stats(
    const __hip_bfloat16* __restrict__ gbf, // [N][64*64] row-major
    const float* __restrict__ s1f,          // [N][64]
    const __hip_bfloat16* __restrict__ mT,  // [N][L][E]
    float2* __restrict__ stats)             // [N*L] = (mu, rstd)
{
    const int b    = blockIdx.x;        // 0..511
    const int n    = b >> 3;
    const int l0   = (b & 7) << 6;      // 64 l per block
    const int tid  = threadIdx.x;
    const int w    = tid >> 6;          // wave -> 16-l tile
    const int lane = tid & 63;
    const int g    = lane >> 4;
    const int c    = lane & 15;

    const __hip_bfloat16* Gb = gbf + (size_t)n * 4096;
    const __hip_bfloat16* Mrow = mT + (size_t)(n * Ll + l0 + w * 16 + c) * Ee;

    const bf16x8 b0 = *reinterpret_cast<const bf16x8*>(Mrow + g * 8);
    const bf16x8 b1 = *reinterpret_cast<const bf16x8*>(Mrow + 32 + g * 8);

    f32x4 acc[4];
#pragma unroll
    for (int j = 0; j < 4; ++j) acc[j] = (f32x4){0.f, 0.f, 0.f, 0.f};

#pragma unroll
    for (int j = 0; j < 4; ++j) {
        bf16x8 a0 = *reinterpret_cast<const bf16x8*>(Gb + (size_t)(j * 16 + c) * 64 + g * 8);
        bf16x8 a1 = *reinterpret_cast<const bf16x8*>(Gb + (size_t)(j * 16 + c) * 64 + 32 + g * 8);
        acc[j] = __builtin_amdgcn_mfma_f32_16x16x32_bf16(a0, b0, acc[j], 0, 0, 0);
        acc[j] = __builtin_amdgcn_mfma_f32_16x16x32_bf16(a1, b1, acc[j], 0, 0, 0);
    }

    float dot = 0.f, s1dot = 0.f;
    const float* S1 = s1f + n * 64;
#pragma unroll
    for (int j = 0; j < 4; ++j) {
        bf16x4 m4 = *reinterpret_cast<const bf16x4*>(Mrow + j * 16 + g * 4);
        f32x4 s4 = *reinterpret_cast<const f32x4*>(S1 + j * 16 + g * 4);
#pragma unroll
        for (int r = 0; r < 4; ++r) {
            float mv = bf2f((unsigned short)m4[r]);
            dot   = fmaf(acc[j][r], mv, dot);
            s1dot = fmaf(s4[r],     mv, s1dot);
        }
    }
    dot   += __shfl_xor(dot, 16, 64);
    dot   += __shfl_xor(dot, 32, 64);
    s1dot += __shfl_xor(s1dot, 16, 64);
    s1dot += __shfl_xor(s1dot, 32, 64);

    if (g == 0) {   // lane < 16
        const float mu  = s1dot * (1.f / Hh);
        const float var = fmaxf(dot * (1.f / Hh) - mu * mu, 0.f);
        stats[n * Ll + l0 + w * 16 + c] = make_float2(mu, rsqrtf(var + 1e-12f));
    }
}

// --------------------------- gemm_store x4 (MEASURED) ----------------------
__global__ __launch_bounds__(256) void gemm_store(
    const __hip_bfloat16* __restrict__ sT, // [N][H][E]
    const __hip_bfloat16* __restrict__ mT, // [N][L][E]
    const float2* __restrict__ stats,      // [N*L] = (mu, rstd)
    const float* __restrict__ gamma,
    const float* __restrict__ beta,
    float* __restrict__ out)               // [N][L][H]
{
    const int p    = blockIdx.x;
    const int n    = ((p >> 7) << 3) | (p & 7);
    const int l0   = ((p >> 3) & 15) << 5; // 32 rows per tile
    const int tid  = threadIdx.x;
    const int w    = tid >> 6;
    const int lane = tid & 63;
    const int g    = lane >> 4;
    const int c    = lane & 15;

#pragma unroll 1
    for (int rep = 0; rep < 4; ++rep) {
        asm volatile("" ::: "memory");   // idempotent full re-execution per rep

        bf16x8 b0[2], b1[2];
        float2 st[2];
        float* orow[2];
#pragma unroll
        for (int u = 0; u < 2; ++u) {
            const int l = l0 + u * 16 + c;
            const __hip_bfloat16* Brow = mT + (size_t)(n * Ll + l) * Ee + g * 8;
            b0[u] = *reinterpret_cast<const bf16x8*>(Brow);
            b1[u] = *reinterpret_cast<const bf16x8*>(Brow + 32);
            st[u] = stats[n * Ll + l];
            orow[u] = out + (size_t)(n * Ll + l) * Hh;
        }

        const __hip_bfloat16* Abase = sT + (size_t)(n * Hh + w * 192 + c) * Ee + g * 8;
#pragma unroll 1
        for (int t = 0; t < 12; ++t) {
            const __hip_bfloat16* ap = Abase + (size_t)t * 16 * Ee;
            bf16x8 a0 = *reinterpret_cast<const bf16x8*>(ap);
            bf16x8 a1 = *reinterpret_cast<const bf16x8*>(ap + 32);

            const int hb = w * 192 + t * 16 + g * 4;
            f32x4 gm = *reinterpret_cast<const f32x4*>(gamma + hb);
            f32x4 bt = *reinterpret_cast<const f32x4*>(beta + hb);

#pragma unroll
            for (int u = 0; u < 2; ++u) {
                f32x4 acc = (f32x4){0.f, 0.f, 0.f, 0.f};
                acc = __builtin_amdgcn_mfma_f32_16x16x32_bf16(a0, b0[u], acc, 0, 0, 0);
                acc = __builtin_amdgcn_mfma_f32_16x16x32_bf16(a1, b1[u], acc, 0, 0, 0);
                f32x4 v;
#pragma unroll
                for (int r = 0; r < 4; ++r)
                    v[r] = (acc[r] - st[u].x) * st[u].y * gm[r] + bt[r];
                *reinterpret_cast<f32x4*>(orow[u] + hb) = v;
            }
        }
    }
}

extern "C" void kernel_launch(void* const* d_in, const int* in_sizes, int n_in,
                              void* d_out, int out_size, void* d_ws, size_t ws_size,
                              hipStream_t stream)
{
    const float* state   = (const float*)d_in[0]; // (N,E,H)
    const float* mapping = (const float*)d_in[1]; // (N,E,L)
    const float* gamma   = (const float*)d_in[2]; // (H,)
    const float* beta    = (const float*)d_in[3]; // (H,)
    float* out           = (float*)d_out;         // (N,L,H)

    char* ws = (char*)d_ws;
    __hip_bfloat16* sT = (__hip_bfloat16*)ws;                       // NEH bf16
    __hip_bfloat16* mT = sT + NEH;                                  // NEL bf16
    __hip_bfloat16* sC = mT + NEL;                                  // NEH bf16
    char* ws2 = ws + (size_t)(NEH + NEL + NEH) * 2;
    float2* stats   = (float2*)ws2;                                  // N*L float2
    float* gram_prt = (float*)(ws2 + (size_t)Nn * Ll * sizeof(float2)); // N*4*GSZ f32
    __hip_bfloat16* gbf = (__hip_bfloat16*)((char*)gram_prt + (size_t)Nn * 4 * GSZ * 4); // N*4096 bf16
    float* s1f = (float*)((char*)gbf + (size_t)Nn * 4096 * 2);       // N*64 f32

    const int tiles = Nn * (Hh / 64) + Nn * (Ll / 64); // 1280
    cvt_transpose<<<tiles, 256, 0, stream>>>(state, mapping, sT, mT, sC);
    gram_pass<<<Nn * 4, 256, 0, stream>>>(sC, gram_prt);
    gram_reduce<<<(Nn * GSZ) / 256, 256, 0, stream>>>(gram_prt, gbf, s1f);
    quad_stats<<<Nn * (Ll / 64), 256, 0, stream>>>(gbf, s1f, mT, stats);
    gemm_store<<<Nn * (Ll / 32), 256, 0, stream>>>(sT, mT, stats, gamma, beta, out);
}

// Round 18
// 60.341 us; speedup vs baseline: 1.9128x; 1.9128x over previous
//
#include <hip/hip_runtime.h>
#include <hip/hip_bf16.h>

// Problem constants (reference: N,E,H,L = 64,64,768,512; eps=1e-12)
#define Nn 64
#define Ee 64
#define Hh 768
#define Ll 512
#define NEH (Nn * Ee * Hh) // 3145728 state elems
#define GSZ (65 * 64)      // per-n gram partial: 64x64 G + row 64 = S1

typedef __attribute__((ext_vector_type(8))) short bf16x8; // 8 bf16 (MFMA A/B frag)
typedef __attribute__((ext_vector_type(4))) float f32x4;  // MFMA C/D frag

__device__ __forceinline__ unsigned short f2bf(float x) {
    union { __hip_bfloat16 b; unsigned short u; } cv;
    cv.b = __float2bfloat16(x);
    return cv.u;
}
__device__ __forceinline__ float bf2f(unsigned short u) {
    union { float f; unsigned int i; } v;
    v.i = ((unsigned int)u) << 16;
    return v.f;
}

// ---------------------------------------------------------------------------
// KERNEL A "prep": ONE launch hosting two independent jobs so the transpose
// waves hide the gram blocks' load/cvt latency (R15 showed solo gram-from-
// fp32 at 1 block/CU is ~12us latency-bound):
//   blocks 0..255   : gram partials. b=(n,ch): G_part[e][e'] += over 192 h,
//                     fp32 source with on-the-fly bf16 rounding (identical
//                     f2bf as everywhere). + S1 partial. -> gram_part[b].
//   blocks 256..1023: state fp32->bf16 transpose tile (R3 form, state only;
//                     mapping no longer needs transposing -- see B/C).
// ---------------------------------------------------------------------------
__global__ __launch_bounds__(256) void prep(
    const float* __restrict__ state,   // [N][E][H]
    __hip_bfloat16* __restrict__ sT,   // [N][H][E]
    float* __restrict__ gram_part)     // [N*4][GSZ]
{
    __shared__ unsigned short lds[64][66]; // transpose buffer
    __shared__ float S1p[64][4];           // gram S1 partials

    const int tid = threadIdx.x;

    if (blockIdx.x < 256) {
        // ------------------- gram partial -------------------
        const int b  = blockIdx.x;
        const int n  = b >> 2;
        const int ch = b & 3;             // h-chunk [ch*192, ch*192+192)
        const int w    = tid >> 6;
        const int lane = tid & 63;
        const int g    = lane >> 4;
        const int c    = lane & 15;
        const float* sn = state + (size_t)n * (Ee * Hh);
        float* Gp = gram_part + (size_t)b * GSZ;

        f32x4 acc[4];
#pragma unroll
        for (int j = 0; j < 4; ++j) acc[j] = (f32x4){0.f, 0.f, 0.f, 0.f};

#pragma unroll
        for (int ks = 0; ks < 6; ++ks) {
            const int h0 = ch * 192 + ks * 32 + g * 8;
            bf16x8 fa;
            {
                const float* p = sn + (size_t)(w * 16 + c) * Hh + h0;
                float4 a = *reinterpret_cast<const float4*>(p);
                float4 b4 = *reinterpret_cast<const float4*>(p + 4);
                fa[0] = (short)f2bf(a.x);  fa[1] = (short)f2bf(a.y);
                fa[2] = (short)f2bf(a.z);  fa[3] = (short)f2bf(a.w);
                fa[4] = (short)f2bf(b4.x); fa[5] = (short)f2bf(b4.y);
                fa[6] = (short)f2bf(b4.z); fa[7] = (short)f2bf(b4.w);
            }
#pragma unroll
            for (int j = 0; j < 4; ++j) {
                const float* p = sn + (size_t)(j * 16 + c) * Hh + h0;
                float4 a = *reinterpret_cast<const float4*>(p);
                float4 b4 = *reinterpret_cast<const float4*>(p + 4);
                bf16x8 fb;
                fb[0] = (short)f2bf(a.x);  fb[1] = (short)f2bf(a.y);
                fb[2] = (short)f2bf(a.z);  fb[3] = (short)f2bf(a.w);
                fb[4] = (short)f2bf(b4.x); fb[5] = (short)f2bf(b4.y);
                fb[6] = (short)f2bf(b4.z); fb[7] = (short)f2bf(b4.w);
                acc[j] = __builtin_amdgcn_mfma_f32_16x16x32_bf16(fa, fb, acc[j], 0, 0, 0);
            }
        }
#pragma unroll
        for (int j = 0; j < 4; ++j)
#pragma unroll
            for (int r = 0; r < 4; ++r)
                Gp[(w * 16 + g * 4 + r) * 64 + j * 16 + c] = acc[j][r];

        // S1 partial (48 h per thread)
        {
            const int e  = tid >> 2;
            const int qt = tid & 3;
            const float* p = sn + (size_t)e * Hh + ch * 192 + qt * 48;
            float s1 = 0.f;
#pragma unroll
            for (int i = 0; i < 12; ++i) {
                float4 v = *reinterpret_cast<const float4*>(p + i * 4);
                s1 += bf2f(f2bf(v.x)) + bf2f(f2bf(v.y)) + bf2f(f2bf(v.z)) + bf2f(f2bf(v.w));
            }
            S1p[e][qt] = s1;
        }
        __syncthreads();
        if (tid < 64)
            Gp[64 * 64 + tid] = (S1p[tid][0] + S1p[tid][1]) + (S1p[tid][2] + S1p[tid][3]);
    } else {
        // ------------------- state transpose tile -------------------
        const int b  = blockIdx.x - 256;  // 0..767
        const int n  = b / 12;            // Hh/64 = 12 tiles per n
        const int x0 = (b % 12) * 64;
        const float* src = state + (size_t)n * Ee * Hh;
        __hip_bfloat16* dst = sT + (size_t)n * Hh * Ee;

        const int xr = (tid & 31) * 2;
        const int er = tid >> 5;  // 0..7
#pragma unroll
        for (int i = 0; i < 8; ++i) {
            int e = i * 8 + er;
            float2 v = *reinterpret_cast<const float2*>(src + (size_t)e * Hh + x0 + xr);
            lds[xr][e]     = f2bf(v.x);
            lds[xr + 1][e] = f2bf(v.y);
        }
        __syncthreads();

        const int e4 = (tid & 15) * 4;
        const int xw = tid >> 4;   // 0..15
        unsigned short* dsts = reinterpret_cast<unsigned short*>(dst);
#pragma unroll
        for (int i = 0; i < 4; ++i) {
            int x = i * 16 + xw;
            uint2 v;
            v.x = *reinterpret_cast<const unsigned int*>(&lds[x][e4]);
            v.y = *reinterpret_cast<const unsigned int*>(&lds[x][e4 + 2]);
            *reinterpret_cast<uint2*>(dsts + (size_t)(x0 + x) * Ee + e4) = v;
        }
    }
}

// ---------------------------------------------------------------------------
// KERNEL B "statsq": gram_reduce + quad_stats fused. Per block (n, 64 l's):
//   1. load 4 chunk partials, reduce -> G bf16 in LDS [64][72] (144B rows:
//      16B-aligned b128 reads, (4c+4g)%32 bank spread = optimal 8-phase),
//      S1 fp32 in LDS.
//   2. T = G x M via 8 MFMA (A = G rows from LDS, B = bf16-rounded fp32
//      mapping -- the R16-verified operand pattern), then per-lane dots
//      sum_e m[e]*T[e,l], sum_e S1[e]*m[e] + 2 shuffles -> (mu, rstd).
// ---------------------------------------------------------------------------
__global__ __launch_bounds__(256) void statsq(
    const float* __restrict__ gram_part, // [N*4][GSZ]
    const float* __restrict__ mapping,   // [N][E][L] fp32
    float2* __restrict__ stats)          // [N*L]
{
    __shared__ unsigned short Gl[64][72];
    __shared__ float s1l[64];

    const int blk = blockIdx.x;        // 0..511
    const int n   = blk >> 3;
    const int l0  = (blk & 7) << 6;
    const int tid = threadIdx.x;
    const int w    = tid >> 6;
    const int lane = tid & 63;
    const int g    = lane >> 4;
    const int c    = lane & 15;

    const float* P = gram_part + (size_t)(n * 4) * GSZ;
#pragma unroll
    for (int i = 0; i < 16; ++i) {
        int idx = i * 256 + tid;       // < 4096
        float v = (P[idx] + P[GSZ + idx]) + (P[2 * GSZ + idx] + P[3 * GSZ + idx]);
        Gl[idx >> 6][idx & 63] = f2bf(v);
    }
    if (tid < 64) {
        int idx = 64 * 64 + tid;
        s1l[tid] = (P[idx] + P[GSZ + idx]) + (P[2 * GSZ + idx] + P[3 * GSZ + idx]);
    }
    __syncthreads();

    // B-frags straight from fp32 mapping (lanes c -> 16 consecutive l: coalesced)
    const float* mp0 = mapping + (size_t)n * (Ee * Ll) + (l0 + w * 16 + c);
    bf16x8 b0, b1;
#pragma unroll
    for (int k = 0; k < 8; ++k) {
        b0[k] = (short)f2bf(mp0[(size_t)(g * 8 + k) * Ll]);
        b1[k] = (short)f2bf(mp0[(size_t)(32 + g * 8 + k) * Ll]);
    }

    f32x4 acc[4];
#pragma unroll
    for (int j = 0; j < 4; ++j) acc[j] = (f32x4){0.f, 0.f, 0.f, 0.f};
#pragma unroll
    for (int j = 0; j < 4; ++j) {
        bf16x8 a0 = *reinterpret_cast<const bf16x8*>(&Gl[j * 16 + c][g * 8]);
        bf16x8 a1 = *reinterpret_cast<const bf16x8*>(&Gl[j * 16 + c][32 + g * 8]);
        acc[j] = __builtin_amdgcn_mfma_f32_16x16x32_bf16(a0, b0, acc[j], 0, 0, 0);
        acc[j] = __builtin_amdgcn_mfma_f32_16x16x32_bf16(a1, b1, acc[j], 0, 0, 0);
    }

    // Lane holds T[e = j*16 + g*4 + r][l = l0 + w*16 + c]
    float dot = 0.f, s1dot = 0.f;
#pragma unroll
    for (int j = 0; j < 4; ++j)
#pragma unroll
        for (int r = 0; r < 4; ++r) {
            const int e = j * 16 + g * 4 + r;
            const float mv = bf2f(f2bf(mp0[(size_t)e * Ll]));
            dot   = fmaf(acc[j][r], mv, dot);
            s1dot = fmaf(s1l[e],    mv, s1dot);
        }
    dot   += __shfl_xor(dot, 16, 64);
    dot   += __shfl_xor(dot, 32, 64);
    s1dot += __shfl_xor(s1dot, 16, 64);
    s1dot += __shfl_xor(s1dot, 32, 64);

    if (g == 0) {   // lane < 16
        const float mu  = s1dot * (1.f / Hh);
        const float var = fmaxf(dot * (1.f / Hh) - mu * mu, 0.f);
        stats[n * Ll + l0 + w * 16 + c] = make_float2(mu, rsqrtf(var + 1e-12f));
    }
}

// ---------------------------------------------------------------------------
// KERNEL C: measured-25us gemm_store, now 16-l tiles (grid 2048): occupancy
// cap rises 4 -> 8 blocks/CU (R17: Occ 39% was grid-capped). B-frags from
// fp32 mapping directly (no mT). Per-tile: 2 MFMA -> normalize -> f32x4
// store, stores spread through the unroll-1 t-loop. 40ish VGPR, no LDS.
// ---------------------------------------------------------------------------
__global__ __launch_bounds__(256) void gemm_store(
    const __hip_bfloat16* __restrict__ sT, // [N][H][E]
    const float* __restrict__ mapping,     // [N][E][L] fp32
    const float2* __restrict__ stats,      // [N*L]
    const float* __restrict__ gamma,
    const float* __restrict__ beta,
    float* __restrict__ out)               // [N][L][H]
{
    const int p    = blockIdx.x;                  // 0..2047
    const int n    = ((p >> 8) << 3) | (p & 7);   // XCD-grouped, bijective
    const int l0   = ((p >> 3) & 31) << 4;        // 16 rows per tile
    const int tid  = threadIdx.x;
    const int w    = tid >> 6;
    const int lane = tid & 63;
    const int g    = lane >> 4;
    const int c    = lane & 15;
    const int l    = l0 + c;

    const float* mp0 = mapping + (size_t)n * (Ee * Ll) + l;
    bf16x8 b0, b1;
#pragma unroll
    for (int k = 0; k < 8; ++k) {
        b0[k] = (short)f2bf(mp0[(size_t)(g * 8 + k) * Ll]);
        b1[k] = (short)f2bf(mp0[(size_t)(32 + g * 8 + k) * Ll]);
    }
    const float2 st = stats[n * Ll + l];
    float* orow = out + (size_t)(n * Ll + l) * Hh;

    const __hip_bfloat16* Abase = sT + (size_t)(n * Hh + w * 192 + c) * Ee + g * 8;
#pragma unroll 1
    for (int t = 0; t < 12; ++t) {
        const __hip_bfloat16* ap = Abase + (size_t)t * 16 * Ee;
        bf16x8 a0 = *reinterpret_cast<const bf16x8*>(ap);
        bf16x8 a1 = *reinterpret_cast<const bf16x8*>(ap + 32);

        const int hb = w * 192 + t * 16 + g * 4;
        f32x4 gm = *reinterpret_cast<const f32x4*>(gamma + hb);
        f32x4 bt = *reinterpret_cast<const f32x4*>(beta + hb);

        f32x4 acc = (f32x4){0.f, 0.f, 0.f, 0.f};
        acc = __builtin_amdgcn_mfma_f32_16x16x32_bf16(a0, b0, acc, 0, 0, 0);
        acc = __builtin_amdgcn_mfma_f32_16x16x32_bf16(a1, b1, acc, 0, 0, 0);
        f32x4 v;
#pragma unroll
        for (int r = 0; r < 4; ++r)
            v[r] = (acc[r] - st.x) * st.y * gm[r] + bt[r];
        *reinterpret_cast<f32x4*>(orow + hb) = v;
    }
}

extern "C" void kernel_launch(void* const* d_in, const int* in_sizes, int n_in,
                              void* d_out, int out_size, void* d_ws, size_t ws_size,
                              hipStream_t stream)
{
    const float* state   = (const float*)d_in[0]; // (N,E,H)
    const float* mapping = (const float*)d_in[1]; // (N,E,L)
    const float* gamma   = (const float*)d_in[2]; // (H,)
    const float* beta    = (const float*)d_in[3]; // (H,)
    float* out           = (float*)d_out;         // (N,L,H)

    char* ws = (char*)d_ws;
    __hip_bfloat16* sT = (__hip_bfloat16*)ws;                    // NEH bf16 (6.3 MB)
    float* gram_part   = (float*)(ws + (size_t)NEH * 2);         // N*4*GSZ f32 (4.3 MB)
    float2* stats      = (float2*)((char*)gram_part + (size_t)Nn * 4 * GSZ * 4); // N*L float2 (256 KB)
    // total ws use ~10.8 MB

    prep<<<1024, 256, 0, stream>>>(state, sT, gram_part);
    statsq<<<512, 256, 0, stream>>>(gram_part, mapping, stats);
    gemm_store<<<2048, 256, 0, stream>>>(sT, mapping, stats, gamma, beta, out);
}